// Round 12
// baseline (2358.158 us; speedup 1.0000x reference)
//
#include <hip/hip_runtime.h>
#include <hip/hip_fp8.h>
#include <stdint.h>

// PM25 transformer forward, MI355X/gfx950. Round 12:
//   - gemm_k: 256x128 tile (was 128x128). Each wave: 64 rows x 128 cols,
//     4 A-frags x 8 B-frags = 64 MFMA/K-step (~310 cy) vs barrier drain
//     (~300-900 cy) -> drain hidden by own compute even at 2 blocks/CU.
//     LDS 48 KB dbuf; acc 128 AGPRs. Block count halves (fewer prolog/epilog).
//     Accumulation order per output unchanged -> absmax bit-identical.
//   - R11 evidence: FETCH halved (XCD remap works ~50%) but dur -6% only ->
//     latency-structure-bound, not locality-bound.
//   - everything else bit-identical to R11.

#define EDIM   384
#define NHEAD  6
#define DHEAD  64
#define NLAYER 6
#define TBLK   36
#define SNUM   210
#define BSZ    1024
#define NTOK   (BSZ*TBLK)
#define QKVSTR 1152
#define KPM    256
#define NHBLK  (NTOK/4)

typedef __attribute__((ext_vector_type(4))) float floatx4;
typedef __attribute__((ext_vector_type(4))) unsigned int uintx4;
typedef __attribute__((ext_vector_type(8))) short short8;

static __device__ __forceinline__ unsigned char f2fp8(float f){
  __hip_fp8_e4m3 t(f); return t.__x;
}
static __device__ __forceinline__ float fp82f(unsigned char u){
  __hip_fp8_e4m3 t; t.__x = u; return (float)t;
}
static __device__ __forceinline__ unsigned short f2bf(float f){
  union { float fv; unsigned int u; } v; v.fv = f;
  unsigned int r = v.u + 0x7FFFu + ((v.u >> 16) & 1u);
  return (unsigned short)(r >> 16);
}
static __device__ __forceinline__ void gld_lds16(const void* g, void* l){
  __builtin_amdgcn_global_load_lds(
      (const __attribute__((address_space(1))) void*)g,
      (__attribute__((address_space(3))) void*)l, 16, 0, 0);
}

// ---------------- weight transpose + fp8 cast: out[m][k] = fp8(in[k][m]) ------
__global__ __launch_bounds__(256) void wt_transpose(const float* __restrict__ in,
    unsigned char* __restrict__ out, int K, int M, long outStride){
  __shared__ float tile[32][33];
  const int mat = blockIdx.z;
  const float* src = in + (size_t)mat*K*M;
  unsigned char* dst = out + (size_t)mat*outStride;
  const int m0 = blockIdx.x*32, k0 = blockIdx.y*32;
  const int tx = threadIdx.x, ty = threadIdx.y;
  for(int i=ty;i<32;i+=8) tile[i][tx] = src[(size_t)(k0+i)*M + m0+tx];
  __syncthreads();
  for(int i=ty;i<32;i+=8) dst[(size_t)(m0+i)*K + k0+tx] = f2fp8(tile[tx][i]);
}

// Wp [210,384] -> wp_t fp8 [384,256] (K zero-padded 210->256)
__global__ __launch_bounds__(256) void wp_transpose(const float* __restrict__ Wp,
    unsigned char* __restrict__ wp_t){
  const int m = blockIdx.x, k = threadIdx.x;
  wp_t[(size_t)m*KPM + k] = (k < SNUM) ? f2fp8(Wp[(size_t)k*EDIM + m]) : 0;
}

// pm fp8 [36864,256]: pm[row][s] = fp8(idx*256/500); x256 undone in epilogue
__global__ __launch_bounds__(256) void prep_pm(const int* __restrict__ idx,
    unsigned char* __restrict__ pm){
  const long i = (long)blockIdx.x*256 + threadIdx.x;
  if(i >= (long)NTOK*KPM) return;
  const int row = i / KPM, s = i - (long)row*KPM;
  float v = 0.f;
  if(s < SNUM) v = (float)idx[((size_t)row*SNUM + s)*2] * (256.f/500.f);
  pm[i] = f2fp8(v);
}

__global__ __launch_bounds__(256) void prep_fire(const int* __restrict__ idx,
    const int* __restrict__ stn_p, int* __restrict__ fire){
  const int row = blockIdx.x*256 + threadIdx.x;
  if(row < NTOK) fire[row] = idx[((size_t)row*SNUM + stn_p[0])*2 + 1];
}

__global__ __launch_bounds__(384) void pe_kernel(float* __restrict__ pe){
  const int t = blockIdx.x, e = threadIdx.x;
  const float freq = __expf(-(float)(2*(e>>1)) * (9.210340371976184f/384.f));
  const float ang = (float)t * freq;
  pe[t*EDIM + e] = (e & 1) ? __cosf(ang) : __sinf(ang);
}

// ---------------- layernorm fp32 -> fp8, one wave per row --------------------
__global__ __launch_bounds__(256) void ln_act(const float* __restrict__ x,
    const float* __restrict__ g, const float* __restrict__ b,
    unsigned char* __restrict__ out){
  const int wave = threadIdx.x >> 6, lane = threadIdx.x & 63;
  const int row = blockIdx.x*4 + wave;
  const float* xr = x + (size_t)row*EDIM;
  float v[6]; float s=0.f, sq=0.f;
  #pragma unroll
  for(int j=0;j<6;j++){ v[j]=xr[j*64+lane]; s+=v[j]; sq+=v[j]*v[j]; }
  #pragma unroll
  for(int m=1;m<64;m<<=1){ s += __shfl_xor(s,m); sq += __shfl_xor(sq,m); }
  const float mean = s*(1.f/384.f);
  const float var  = sq*(1.f/384.f) - mean*mean;
  const float rstd = rsqrtf(var + 1e-5f);
  unsigned char* orow = out + (size_t)row*EDIM;
  #pragma unroll
  for(int j=0;j<6;j++){
    int e = j*64+lane;
    orow[e] = f2fp8((v[j]-mean)*rstd*g[e] + b[e]);
  }
}

// ---------------- fp8 MFMA GEMM, 256x128, BK=64, dbuf, XCD-remapped -----------
// 4 waves; wave owns 64 rows x 128 cols (4 A-frags x 8 B-frags, 64 MFMA/step).
// grid (ncol, nrow/2); nrow tiles (=gridDim.y) must be divisible by 8.
// MODE 0: write fp8 via LDS repack + dwordx4 (bias opt, RELU opt).
// MODE 1: fp32 residual accumulate: x += val + bias.
// MODE 2: embed epilogue (val/256 + bp + stat + pe + fire_emb) -> fp32 x.
template<int MODE, bool RELU>
__global__ __launch_bounds__(256) void gemm_k(const unsigned char* __restrict__ A,
    const unsigned char* __restrict__ Wt, const float* __restrict__ bias,
    unsigned char* __restrict__ outb, float* __restrict__ xout,
    const int* __restrict__ fire, const float* __restrict__ pe,
    const float* __restrict__ stat_emb, const int* __restrict__ stn_p,
    const float* __restrict__ fire_emb, int M, int K){
  __shared__ __align__(16) unsigned char As[2][256*64];   // 2x16 KB
  __shared__ __align__(16) unsigned char Bs[2][128*64];   // 2x8 KB
  const int tid  = threadIdx.x;
  // XCD-aware remap (row tile owned by one XCD; nrow tiles % 8 == 0)
  const int ncol = gridDim.x;
  const int lin  = blockIdx.x + ncol*blockIdx.y;
  const int xcd  = lin & 7;
  const int per  = lin >> 3;
  const int m0   = (per % ncol) * 128;
  const int n0   = ((per / ncol)*8 + xcd) * 256;
  const int wave = tid >> 6, lane = tid & 63;
  const int lrow = lane & 15, quad = lane >> 4;
  const int lsw = (lrow & 3) ^ ((lrow >> 2) & 3);
  floatx4 acc[4][8];
  #pragma unroll
  for(int i=0;i<4;i++)
    #pragma unroll
    for(int j=0;j<8;j++) acc[i][j] = (floatx4){0.f,0.f,0.f,0.f};

  const int S = K >> 6;
  auto stage = [&](int s, int bi){
    const int kk = s*64;
    #pragma unroll
    for(int p=0;p<4;p++){
      int i = tid + p*256;
      int r = i >> 2, jp = i & 3;
      int jl = jp ^ (r & 3) ^ ((r >> 2) & 3);
      gld_lds16(&A[(size_t)(n0+r)*K + kk + jl*16], &As[bi][i*16]);
    }
    #pragma unroll
    for(int p=0;p<2;p++){
      int i = tid + p*256;
      int r = i >> 2, jp = i & 3;
      int jl = jp ^ (r & 3) ^ ((r >> 2) & 3);
      gld_lds16(&Wt[(size_t)(m0+r)*K + kk + jl*16], &Bs[bi][i*16]);
    }
  };
  stage(0, 0);
  for(int s=0; s<S; s++){
    const int bi = s & 1;
    __syncthreads();
    if(s+1 < S) stage(s+1, bi^1);
    #pragma unroll
    for(int ks=0; ks<2; ks++){
      const int joff = (((ks*2 + (quad>>1)) ^ lsw) << 4) + (quad & 1)*8;
      long af[4], bfv[8];
      #pragma unroll
      for(int ti=0;ti<4;ti++)
        af[ti]  = *(const long*)(&As[bi][(wave*64+ti*16+lrow)*64 + joff]);
      #pragma unroll
      for(int tj=0;tj<8;tj++)
        bfv[tj] = *(const long*)(&Bs[bi][(tj*16+lrow)*64 + joff]);
      #pragma unroll
      for(int ti=0;ti<4;ti++)
        #pragma unroll
        for(int tj=0;tj<8;tj++)
          acc[ti][tj] = __builtin_amdgcn_mfma_f32_16x16x32_fp8_fp8(af[ti], bfv[tj], acc[ti][tj], 0,0,0);
    }
  }
  if(MODE==0){
    __syncthreads();
    unsigned char* Cs = (unsigned char*)&As[0][0];   // 32 KB == sizeof(As)
    #pragma unroll
    for(int ti=0;ti<4;ti++){
      #pragma unroll
      for(int tj=0;tj<8;tj++){
        const int col = tj*16 + lrow;
        const float bi = bias ? bias[m0+col] : 0.f;
        #pragma unroll
        for(int r=0;r<4;r++){
          const int row = wave*64 + ti*16 + quad*4 + r;
          float val = acc[ti][tj][r] + bi;
          if(RELU) val = fmaxf(val, 0.f);
          Cs[row*128 + col] = f2fp8(val);
        }
      }
    }
    __syncthreads();
    #pragma unroll
    for(int p=0;p<8;p++){
      const int q = tid + p*256;
      const int row = q >> 3, c16 = (q & 7)*16;
      *(uintx4*)(&outb[(size_t)(n0+row)*M + m0 + c16]) =
          *(const uintx4*)(&Cs[row*128 + c16]);
    }
  } else {
    const int stn = (MODE==2) ? stn_p[0] : 0;
    #pragma unroll
    for(int ti=0;ti<4;ti++){
      #pragma unroll
      for(int r=0;r<4;r++){
        int row = n0 + wave*64 + ti*16 + quad*4 + r;
        int fidx = 0, trow = 0;
        if(MODE==2){ fidx = fire[row]; trow = row % TBLK; }
        #pragma unroll
        for(int tj=0;tj<8;tj++){
          int col = m0 + tj*16 + lrow;
          float val = acc[ti][tj][r];
          if(MODE==1){
            xout[(size_t)row*EDIM + col] += val + bias[col];
          } else {
            val = val*(1.f/256.f) + bias[col] + stat_emb[(size_t)stn*EDIM + col]
                + pe[trow*EDIM + col] + fire_emb[(size_t)fidx*EDIM + col];
            xout[(size_t)row*EDIM + col] = val;
          }
        }
      }
    }
  }
}

// ------- full-row GEMM + residual + LayerNorm epilogue (Wo only, K=384) -------
__global__ __launch_bounds__(512, 4) void gemm_row_ln(
    const unsigned char* __restrict__ A, const unsigned char* __restrict__ Wt,
    const float* __restrict__ bias, float* __restrict__ x,
    const float* __restrict__ g, const float* __restrict__ b,
    unsigned char* __restrict__ h, int K, int writeH){
  __shared__ __align__(16) unsigned char As[2][64*32];     // 2x2 KB
  __shared__ __align__(16) unsigned char Bs[2][384*32];    // 2x12 KB
  const int tid = threadIdx.x;
  const int n0 = blockIdx.x * 64;
  const int wave = tid >> 6, lane = tid & 63;
  const int rw = wave >> 1, cw = wave & 1;
  const int lrow = lane & 15, quad = lane >> 4;
  const int xsw = ((lane >> 2) & 1) << 4;
  floatx4 acc[12];
  #pragma unroll
  for(int j=0;j<12;j++) acc[j] = (floatx4){0.f,0.f,0.f,0.f};

  const int S = K >> 5;
  auto stage = [&](int s, int bi){
    const int kk = s*32;
    if(tid < 128){
      int r = tid >> 1, c = (((tid&1) ^ ((tid>>3)&1))) * 16;
      gld_lds16(&A[(size_t)(n0+r)*K + kk + c], &As[bi][tid*16]);
    }
    {
      int i = tid;
      int r = i >> 1, c = (((i&1) ^ ((i>>3)&1))) * 16;
      gld_lds16(&Wt[(size_t)r*K + kk + c], &Bs[bi][i*16]);
    }
    if(tid < 256){
      int i = tid + 512;
      int r = i >> 1, c = (((i&1) ^ ((i>>3)&1))) * 16;
      gld_lds16(&Wt[(size_t)r*K + kk + c], &Bs[bi][i*16]);
    }
  };
  stage(0, 0);
  for(int s=0; s<S; s++){
    const int bi = s & 1;
    __syncthreads();
    if(s+1 < S) stage(s+1, bi^1);
    long af = *(const long*)(&As[bi][(rw*16+lrow)*32 + ((quad*8) ^ xsw)]);
    long bfv[12];
    #pragma unroll
    for(int tj=0;tj<12;tj++)
      bfv[tj] = *(const long*)(&Bs[bi][(cw*192+tj*16+lrow)*32 + ((quad*8) ^ xsw)]);
    #pragma unroll
    for(int tj=0;tj<12;tj++)
      acc[tj] = __builtin_amdgcn_mfma_f32_16x16x32_fp8_fp8(af, bfv[tj], acc[tj], 0,0,0);
  }
  __syncthreads();
  float* part = (float*)&As[0][0];
  {
    float ps[4] = {0.f,0.f,0.f,0.f}, pq[4] = {0.f,0.f,0.f,0.f};
    #pragma unroll
    for(int tj=0;tj<12;tj++){
      const int col = cw*192 + tj*16 + lrow;
      const float bi = bias[col];
      #pragma unroll
      for(int r=0;r<4;r++){
        const int row = n0 + rw*16 + quad*4 + r;
        float v = acc[tj][r] + bi + x[(size_t)row*EDIM + col];
        acc[tj][r] = v;
        ps[r] += v; pq[r] += v*v;
      }
    }
    #pragma unroll
    for(int r=0;r<4;r++){
      #pragma unroll
      for(int m=1;m<16;m<<=1){ ps[r] += __shfl_xor(ps[r],m); pq[r] += __shfl_xor(pq[r],m); }
    }
    if(lrow == 0){
      #pragma unroll
      for(int r=0;r<4;r++){
        const int rl = rw*16 + quad*4 + r;
        part[rl*2 + cw]       = ps[r];
        part[128 + rl*2 + cw] = pq[r];
      }
    }
  }
  __syncthreads();
  #pragma unroll
  for(int r=0;r<4;r++){
    const int rl = rw*16 + quad*4 + r;
    const int row = n0 + rl;
    const float s = part[rl*2+0] + part[rl*2+1];
    const float q = part[128+rl*2+0] + part[128+rl*2+1];
    const float mean = s*(1.f/384.f);
    const float var  = q*(1.f/384.f) - mean*mean;
    const float rstd = rsqrtf(var + 1e-5f);
    #pragma unroll
    for(int tj=0;tj<12;tj++){
      const int col = cw*192 + tj*16 + lrow;
      const float v = acc[tj][r];
      x[(size_t)row*EDIM + col] = v;
      if(writeH)
        h[(size_t)row*EDIM + col] = f2fp8((v-mean)*rstd*g[col] + b[col]);
    }
  }
}

// ---------------- MFMA attention: one wave per (b,h), no cross-wave sync ------
__global__ __launch_bounds__(256) void attn_kernel(const unsigned char* __restrict__ qkv,
    unsigned char* __restrict__ o){
  __shared__ __align__(16) unsigned short lds[4*8064];   // 63 KB
  const int wave = threadIdx.x >> 6, lane = threadIdx.x & 63;
  const int bh = blockIdx.x*4 + wave;
  const int b = bh / NHEAD, h = bh % NHEAD;
  const int lrow = lane & 15, quad = lane >> 4;
  unsigned short* PT = lds + wave*8064;    // [48][72]
  unsigned short* VT = PT + 48*72;         // [64][72]
  const size_t base = (size_t)b*TBLK*QKVSTR + h*DHEAD;
  const unsigned char* qp = qkv + base;
  const unsigned char* kp = qkv + base + 384;
  const unsigned char* vp = qkv + base + 768;

  for(int s=0;s<64;s++){
    float v = (s < TBLK) ? fp82f(vp[(size_t)s*QKVSTR + lane]) : 0.f;
    VT[lane*72 + s] = f2bf(v);
  }
  #pragma unroll
  for(int i=lane;i<96;i+=64){
    int row = i >> 1, c = (i & 1)*8;
    *(short8*)(&PT[row*72 + 48 + c]) = (short8){0,0,0,0,0,0,0,0};
  }

  floatx4 accs[3][3];
  #pragma unroll
  for(int i=0;i<3;i++)
    #pragma unroll
    for(int j=0;j<3;j++) accs[i][j] = (floatx4){0.f,0.f,0.f,0.f};
  #pragma unroll
  for(int ks=0;ks<2;ks++){
    long aq[3], bk[3];
    #pragma unroll
    for(int ti=0;ti<3;ti++)
      aq[ti] = *(const long*)(qp + (size_t)(ti*16+lrow)*QKVSTR + ks*32 + quad*8);
    #pragma unroll
    for(int tj=0;tj<3;tj++)
      bk[tj] = *(const long*)(kp + (size_t)(tj*16+lrow)*QKVSTR + ks*32 + quad*8);
    #pragma unroll
    for(int ti=0;ti<3;ti++)
      #pragma unroll
      for(int tj=0;tj<3;tj++)
        accs[ti][tj] = __builtin_amdgcn_mfma_f32_16x16x32_fp8_fp8(aq[ti], bk[tj], accs[ti][tj], 0,0,0);
  }

  const float scale = 0.125f;
  #pragma unroll
  for(int ti=0;ti<3;ti++){
    #pragma unroll
    for(int r=0;r<4;r++){
      const int t = ti*16 + quad*4 + r;
      float pv[3]; float mx = -INFINITY;
      #pragma unroll
      for(int tj=0;tj<3;tj++){
        const int s = tj*16 + lrow;
        pv[tj] = (s <= t) ? accs[ti][tj][r]*scale : -INFINITY;
        mx = fmaxf(mx, pv[tj]);
      }
      #pragma unroll
      for(int m=1;m<16;m<<=1) mx = fmaxf(mx, __shfl_xor(mx, m));
      float sum = 0.f;
      #pragma unroll
      for(int tj=0;tj<3;tj++){ pv[tj] = __expf(pv[tj]-mx); sum += pv[tj]; }
      #pragma unroll
      for(int m=1;m<16;m<<=1) sum += __shfl_xor(sum, m);
      const float rs = 1.f/sum;
      #pragma unroll
      for(int tj=0;tj<3;tj++)
        PT[t*72 + tj*16 + lrow] = f2bf(pv[tj]*rs);
    }
  }

  floatx4 acco[3][4];
  #pragma unroll
  for(int i=0;i<3;i++)
    #pragma unroll
    for(int j=0;j<4;j++) acco[i][j] = (floatx4){0.f,0.f,0.f,0.f};
  #pragma unroll
  for(int ks=0;ks<2;ks++){
    short8 ap[3], bv[4];
    #pragma unroll
    for(int ti=0;ti<3;ti++)
      ap[ti] = *(const short8*)(&PT[(ti*16+lrow)*72 + ks*32 + quad*8]);
    #pragma unroll
    for(int td=0;td<4;td++)
      bv[td] = *(const short8*)(&VT[(td*16+lrow)*72 + ks*32 + quad*8]);
    #pragma unroll
    for(int ti=0;ti<3;ti++)
      #pragma unroll
      for(int td=0;td<4;td++)
        acco[ti][td] = __builtin_amdgcn_mfma_f32_16x16x32_bf16(ap[ti], bv[td], acco[ti][td], 0,0,0);
  }

  unsigned char* OB = (unsigned char*)VT;    // [48][80]
  #pragma unroll
  for(int ti=0;ti<3;ti++)
    #pragma unroll
    for(int td=0;td<4;td++)
      #pragma unroll
      for(int r=0;r<4;r++)
        OB[(ti*16+quad*4+r)*80 + td*16 + lrow] = f2fp8(acco[ti][td][r]);
  for(int i=lane;i<TBLK*4;i+=64){
    const int row = i >> 2, c16 = (i & 3)*16;
    *(uintx4*)(&o[((size_t)b*TBLK+row)*EDIM + h*DHEAD + c16]) =
        *(const uintx4*)(&OB[row*80 + c16]);
  }
}

// ---------------- head: LNf + sigmoid(x@Wh+bh)*500 + per-block partials -------
__global__ __launch_bounds__(256) void head_kernel(const float* __restrict__ x,
    const float* __restrict__ g, const float* __restrict__ b,
    const float* __restrict__ Wh, const float* __restrict__ bh,
    const int* __restrict__ targets, float* __restrict__ out,
    float* __restrict__ partials){
  const int wave = threadIdx.x >> 6, lane = threadIdx.x & 63;
  const int row = blockIdx.x*4 + wave;
  const float* xr = x + (size_t)row*EDIM;
  float v[6]; float s=0.f, sq=0.f;
  #pragma unroll
  for(int j=0;j<6;j++){ v[j]=xr[j*64+lane]; s+=v[j]; sq+=v[j]*v[j]; }
  #pragma unroll
  for(int m=1;m<64;m<<=1){ s += __shfl_xor(s,m); sq += __shfl_xor(sq,m); }
  const float mean = s*(1.f/384.f);
  const float var  = sq*(1.f/384.f) - mean*mean;
  const float rstd = rsqrtf(var + 1e-5f);
  float dot = 0.f;
  #pragma unroll
  for(int j=0;j<6;j++){
    int e = j*64+lane;
    float hh = (v[j]-mean)*rstd*g[e] + b[e];
    dot = fmaf(hh, Wh[e], dot);
  }
  #pragma unroll
  for(int m=1;m<64;m<<=1) dot += __shfl_xor(dot,m);
  __shared__ float part[4][4];
  if(lane == 0){
    float logit = 1.f/(1.f + __expf(-(dot + bh[0])));
    float den = logit * 500.f;
    out[row] = den;
    float tgt = (float)targets[(size_t)row*2];
    float nt  = tgt * (1.f/500.f);
    part[wave][0] = (logit-nt)*(logit-nt);
    part[wave][1] = (tgt-den)*(tgt-den);
    part[wave][2] = tgt;
    part[wave][3] = tgt*tgt;
  }
  __syncthreads();
  if(threadIdx.x < 4){
    float t0 = part[0][threadIdx.x] + part[1][threadIdx.x]
             + part[2][threadIdx.x] + part[3][threadIdx.x];
    partials[(size_t)threadIdx.x*NHBLK + blockIdx.x] = t0;
  }
}

// ---------------- final reduction: partials[4][NHBLK] -> mse, r2 --------------
__global__ __launch_bounds__(1024) void finalize_reduce(
    const float* __restrict__ partials, float* __restrict__ out){
  __shared__ float red[16];
  const int tid = threadIdx.x;
  const int c = tid >> 8, j = tid & 255;
  float s = 0.f;
  for(int i = j; i < NHBLK; i += 256) s += partials[(size_t)c*NHBLK + i];
  #pragma unroll
  for(int m=1;m<64;m<<=1) s += __shfl_xor(s,m);
  if((tid & 63) == 0) red[tid >> 6] = s;
  __syncthreads();
  if(tid == 0){
    float a0 = red[0]+red[1]+red[2]+red[3];
    float a1 = red[4]+red[5]+red[6]+red[7];
    float a2 = red[8]+red[9]+red[10]+red[11];
    float a3 = red[12]+red[13]+red[14]+red[15];
    const float n = (float)NTOK;
    out[NTOK]   = a0 / n;
    float denom = a3 - a2*a2/n;
    out[NTOK+1] = 1.f - a1/denom;
  }
}

// =============================================================================
extern "C" void kernel_launch(void* const* d_in, const int* in_sizes, int n_in,
                              void* d_out, int out_size, void* d_ws, size_t ws_size,
                              hipStream_t stream){
  (void)in_sizes; (void)n_in; (void)out_size; (void)ws_size;
  const int*   idx      = (const int*)  d_in[0];
  const int*   targets  = (const int*)  d_in[1];
  const int*   stn_ix   = (const int*)  d_in[3];
  const float* Wp       = (const float*)d_in[4];
  const float* bp       = (const float*)d_in[5];
  const float* stat_emb = (const float*)d_in[6];
  const float* fire_emb = (const float*)d_in[7];
  const float* ln1_g    = (const float*)d_in[8];
  const float* ln1_b    = (const float*)d_in[9];
  const float* Wq       = (const float*)d_in[10];
  const float* Wk       = (const float*)d_in[11];
  const float* Wv       = (const float*)d_in[12];
  const float* Wo       = (const float*)d_in[13];
  const float* bo       = (const float*)d_in[14];
  const float* ln2_g    = (const float*)d_in[15];
  const float* ln2_b    = (const float*)d_in[16];
  const float* W1       = (const float*)d_in[17];
  const float* b1       = (const float*)d_in[18];
  const float* W2       = (const float*)d_in[19];
  const float* b2       = (const float*)d_in[20];
  const float* lnf_g    = (const float*)d_in[21];
  const float* lnf_b    = (const float*)d_in[22];
  const float* Wh       = (const float*)d_in[23];
  const float* bh       = (const float*)d_in[24];
  float* out = (float*)d_out;

  char* ws = (char*)d_ws;
  float*         x      = (float*)        (ws + 0);
  unsigned char* h      = (unsigned char*)(ws + 56623104);
  unsigned char* qkv    = (unsigned char*)(ws + 84934656);
  unsigned char* obuf   = (unsigned char*)(ws + 169869312);
  unsigned char* ffn    = qkv;
  unsigned char* pm     = (unsigned char*)(ws + 169869312);  // aliases obuf
  int*           fire   = (int*)          (ws + 186384384);
  unsigned char* wp_t   = (unsigned char*)(ws + 186531840);
  float*         pe     = (float*)        (ws + 186703872);
  float*         partials = (float*)      (ws + 169869312);  // aliases obuf
  unsigned char* wqkv_t = (unsigned char*)(ws + 198180864);
  unsigned char* wo_t   = (unsigned char*)(ws + 203489280);
  unsigned char* w1_t   = (unsigned char*)(ws + 205258752);
  unsigned char* w2_t   = (unsigned char*)(ws + 212336640);

  const dim3 tb(32,8);
  wt_transpose<<<dim3(12,12,6), tb, 0, stream>>>(Wq, wqkv_t,          384,  384, 442368);
  wt_transpose<<<dim3(12,12,6), tb, 0, stream>>>(Wk, wqkv_t + 147456, 384,  384, 442368);
  wt_transpose<<<dim3(12,12,6), tb, 0, stream>>>(Wv, wqkv_t + 294912, 384,  384, 442368);
  wt_transpose<<<dim3(12,12,6), tb, 0, stream>>>(Wo, wo_t,            384,  384, 147456);
  wt_transpose<<<dim3(48,12,6), tb, 0, stream>>>(W1, w1_t,            384, 1536, 589824);
  wt_transpose<<<dim3(12,48,6), tb, 0, stream>>>(W2, w2_t,           1536,  384, 589824);
  wp_transpose<<<384, 256, 0, stream>>>(Wp, wp_t);
  pe_kernel<<<TBLK, 384, 0, stream>>>(pe);
  prep_pm<<<(NTOK*KPM + 255)/256, 256, 0, stream>>>(idx, pm);
  prep_fire<<<(NTOK + 255)/256, 256, 0, stream>>>(idx, stn_ix, fire);

  // embed GEMM: x = (pm*256) @ wp_t^T / 256 + (bp + stat + pe + fire_emb)
  gemm_k<2,false><<<dim3(3,144), 256, 0, stream>>>(pm, wp_t, bp, nullptr, x,
      fire, pe, stat_emb, stn_ix, fire_emb, 384, KPM);

  // layer-0 ln1
  ln_act<<<NTOK/4, 256, 0, stream>>>(x, ln1_g, ln1_b, h);

  const dim3 gQKV(9, 144);
  const dim3 gE(3, 144);
  const dim3 gF(12, 144);
  for(int l=0; l<NLAYER; l++){
    gemm_k<0,false><<<gQKV, 256, 0, stream>>>(h, wqkv_t + (size_t)l*442368,
        nullptr, qkv, nullptr, nullptr, nullptr, nullptr, nullptr, nullptr, 1152, 384);
    attn_kernel<<<BSZ*NHEAD/4, 256, 0, stream>>>(qkv, obuf);
    // x += obuf@Wo + bo;  h = LN2(x)   (fused; K=384)
    gemm_row_ln<<<NTOK/64, 512, 0, stream>>>(obuf, wo_t + (size_t)l*147456,
        bo + l*EDIM, x, ln2_g + l*EDIM, ln2_b + l*EDIM, h, 384, 1);
    gemm_k<0,true><<<gF, 256, 0, stream>>>(h, w1_t + (size_t)l*589824,
        b1 + l*1536, ffn, nullptr, nullptr, nullptr, nullptr, nullptr, nullptr, 1536, 384);
    // x += ffn@W2 + b2   (fp8, fp32 residual epilogue)
    gemm_k<1,false><<<gE, 256, 0, stream>>>(ffn, w2_t + (size_t)l*589824,
        b2 + l*EDIM, nullptr, x, nullptr, nullptr, nullptr, nullptr, nullptr, 384, 1536);
    // h = LN1[l+1](x)  (skip on last layer; head does LNf itself)
    if(l < NLAYER-1)
      ln_act<<<NTOK/4, 256, 0, stream>>>(x, ln1_g + (l+1)*EDIM, ln1_b + (l+1)*EDIM, h);
  }

  head_kernel<<<NHBLK, 256, 0, stream>>>(x, lnf_g, lnf_b, Wh, bh, targets, out, partials);
  finalize_reduce<<<1, 1024, 0, stream>>>(partials, out);
}

// Round 13
// 1810.431 us; speedup vs baseline: 1.3025x; 1.3025x over previous
//
#include <hip/hip_runtime.h>
#include <hip/hip_fp8.h>
#include <stdint.h>

// PM25 transformer forward, MI355X/gfx950. Round 13: REVERT gemm_k to R11
// (128x128, BK=64, dbuf, XCD remap; 96 VGPR + 64 AGPR -> 3 waves/SIMD).
// R12's 256x128 tile hit the occupancy cliff (264 regs/wave -> 1 block/CU,
// Occupancy 10.5%, W1 61->104 us): density-vs-occupancy falsifier triggered.
// R11 is the measured optimum of this kernel family's config space.

#define EDIM   384
#define NHEAD  6
#define DHEAD  64
#define NLAYER 6
#define TBLK   36
#define SNUM   210
#define BSZ    1024
#define NTOK   (BSZ*TBLK)
#define QKVSTR 1152
#define KPM    256
#define NHBLK  (NTOK/4)

typedef __attribute__((ext_vector_type(4))) float floatx4;
typedef __attribute__((ext_vector_type(4))) unsigned int uintx4;
typedef __attribute__((ext_vector_type(8))) short short8;

static __device__ __forceinline__ unsigned char f2fp8(float f){
  __hip_fp8_e4m3 t(f); return t.__x;
}
static __device__ __forceinline__ float fp82f(unsigned char u){
  __hip_fp8_e4m3 t; t.__x = u; return (float)t;
}
static __device__ __forceinline__ unsigned short f2bf(float f){
  union { float fv; unsigned int u; } v; v.fv = f;
  unsigned int r = v.u + 0x7FFFu + ((v.u >> 16) & 1u);
  return (unsigned short)(r >> 16);
}
static __device__ __forceinline__ void gld_lds16(const void* g, void* l){
  __builtin_amdgcn_global_load_lds(
      (const __attribute__((address_space(1))) void*)g,
      (__attribute__((address_space(3))) void*)l, 16, 0, 0);
}

// ---------------- weight transpose + fp8 cast: out[m][k] = fp8(in[k][m]) ------
__global__ __launch_bounds__(256) void wt_transpose(const float* __restrict__ in,
    unsigned char* __restrict__ out, int K, int M, long outStride){
  __shared__ float tile[32][33];
  const int mat = blockIdx.z;
  const float* src = in + (size_t)mat*K*M;
  unsigned char* dst = out + (size_t)mat*outStride;
  const int m0 = blockIdx.x*32, k0 = blockIdx.y*32;
  const int tx = threadIdx.x, ty = threadIdx.y;
  for(int i=ty;i<32;i+=8) tile[i][tx] = src[(size_t)(k0+i)*M + m0+tx];
  __syncthreads();
  for(int i=ty;i<32;i+=8) dst[(size_t)(m0+i)*K + k0+tx] = f2fp8(tile[tx][i]);
}

// Wp [210,384] -> wp_t fp8 [384,256] (K zero-padded 210->256)
__global__ __launch_bounds__(256) void wp_transpose(const float* __restrict__ Wp,
    unsigned char* __restrict__ wp_t){
  const int m = blockIdx.x, k = threadIdx.x;
  wp_t[(size_t)m*KPM + k] = (k < SNUM) ? f2fp8(Wp[(size_t)k*EDIM + m]) : 0;
}

// pm fp8 [36864,256]: pm[row][s] = fp8(idx*256/500); x256 undone in epilogue
__global__ __launch_bounds__(256) void prep_pm(const int* __restrict__ idx,
    unsigned char* __restrict__ pm){
  const long i = (long)blockIdx.x*256 + threadIdx.x;
  if(i >= (long)NTOK*KPM) return;
  const int row = i / KPM, s = i - (long)row*KPM;
  float v = 0.f;
  if(s < SNUM) v = (float)idx[((size_t)row*SNUM + s)*2] * (256.f/500.f);
  pm[i] = f2fp8(v);
}

__global__ __launch_bounds__(256) void prep_fire(const int* __restrict__ idx,
    const int* __restrict__ stn_p, int* __restrict__ fire){
  const int row = blockIdx.x*256 + threadIdx.x;
  if(row < NTOK) fire[row] = idx[((size_t)row*SNUM + stn_p[0])*2 + 1];
}

__global__ __launch_bounds__(384) void pe_kernel(float* __restrict__ pe){
  const int t = blockIdx.x, e = threadIdx.x;
  const float freq = __expf(-(float)(2*(e>>1)) * (9.210340371976184f/384.f));
  const float ang = (float)t * freq;
  pe[t*EDIM + e] = (e & 1) ? __cosf(ang) : __sinf(ang);
}

// ---------------- layernorm fp32 -> fp8, one wave per row --------------------
__global__ __launch_bounds__(256) void ln_act(const float* __restrict__ x,
    const float* __restrict__ g, const float* __restrict__ b,
    unsigned char* __restrict__ out){
  const int wave = threadIdx.x >> 6, lane = threadIdx.x & 63;
  const int row = blockIdx.x*4 + wave;
  const float* xr = x + (size_t)row*EDIM;
  float v[6]; float s=0.f, sq=0.f;
  #pragma unroll
  for(int j=0;j<6;j++){ v[j]=xr[j*64+lane]; s+=v[j]; sq+=v[j]*v[j]; }
  #pragma unroll
  for(int m=1;m<64;m<<=1){ s += __shfl_xor(s,m); sq += __shfl_xor(sq,m); }
  const float mean = s*(1.f/384.f);
  const float var  = sq*(1.f/384.f) - mean*mean;
  const float rstd = rsqrtf(var + 1e-5f);
  unsigned char* orow = out + (size_t)row*EDIM;
  #pragma unroll
  for(int j=0;j<6;j++){
    int e = j*64+lane;
    orow[e] = f2fp8((v[j]-mean)*rstd*g[e] + b[e]);
  }
}

// ---------------- fp8 MFMA GEMM, 128x128, BK=64, dbuf, XCD-remapped -----------
// MODE 0: write fp8 via LDS repack + dwordx4 (bias opt, RELU opt).
// MODE 1: fp32 residual accumulate: x += val + bias.
// MODE 2: embed epilogue (val/256 + bp + stat + pe + fire_emb) -> fp32 x.
template<int MODE, bool RELU>
__global__ __launch_bounds__(256) void gemm_k(const unsigned char* __restrict__ A,
    const unsigned char* __restrict__ Wt, const float* __restrict__ bias,
    unsigned char* __restrict__ outb, float* __restrict__ xout,
    const int* __restrict__ fire, const float* __restrict__ pe,
    const float* __restrict__ stat_emb, const int* __restrict__ stn_p,
    const float* __restrict__ fire_emb, int M, int K){
  __shared__ __align__(16) unsigned char As[2][128*64];   // 2x8 KB
  __shared__ __align__(16) unsigned char Bs[2][128*64];   // 2x8 KB
  const int tid  = threadIdx.x;
  // XCD-aware remap: same-row col-tiles land consecutively on one XCD so the
  // A-tile is fetched once into that XCD's private L2.
  const int ncol = gridDim.x;
  const int lin  = blockIdx.x + ncol*blockIdx.y;
  const int xcd  = lin & 7;
  const int per  = lin >> 3;
  const int m0   = (per % ncol) * 128;
  const int n0   = ((per / ncol)*8 + xcd) * 128;
  const int wave = tid >> 6, lane = tid & 63;
  const int wr = wave >> 1, wc = wave & 1;
  const int lrow = lane & 15, quad = lane >> 4;
  const int lsw = (lrow & 3) ^ ((lrow >> 2) & 3);
  floatx4 acc[4][4];
  #pragma unroll
  for(int i=0;i<4;i++)
    #pragma unroll
    for(int j=0;j<4;j++) acc[i][j] = (floatx4){0.f,0.f,0.f,0.f};

  const int S = K >> 6;
  auto stage = [&](int s, int bi){
    const int kk = s*64;
    #pragma unroll
    for(int p=0;p<2;p++){
      int i = tid + p*256;
      int r = i >> 2, jp = i & 3;
      int jl = jp ^ (r & 3) ^ ((r >> 2) & 3);
      gld_lds16(&A [(size_t)(n0+r)*K + kk + jl*16], &As[bi][i*16]);
      gld_lds16(&Wt[(size_t)(m0+r)*K + kk + jl*16], &Bs[bi][i*16]);
    }
  };
  stage(0, 0);
  for(int s=0; s<S; s++){
    const int bi = s & 1;
    __syncthreads();
    if(s+1 < S) stage(s+1, bi^1);
    #pragma unroll
    for(int ks=0; ks<2; ks++){
      const int joff = (((ks*2 + (quad>>1)) ^ lsw) << 4) + (quad & 1)*8;
      long af[4], bfv[4];
      #pragma unroll
      for(int ti=0;ti<4;ti++)
        af[ti]  = *(const long*)(&As[bi][(wr*64+ti*16+lrow)*64 + joff]);
      #pragma unroll
      for(int tj=0;tj<4;tj++)
        bfv[tj] = *(const long*)(&Bs[bi][(wc*64+tj*16+lrow)*64 + joff]);
      #pragma unroll
      for(int ti=0;ti<4;ti++)
        #pragma unroll
        for(int tj=0;tj<4;tj++)
          acc[ti][tj] = __builtin_amdgcn_mfma_f32_16x16x32_fp8_fp8(af[ti], bfv[tj], acc[ti][tj], 0,0,0);
    }
  }
  if(MODE==0){
    __syncthreads();
    unsigned char* Cs = (unsigned char*)&As[0][0];   // 16 KB == sizeof(As)
    #pragma unroll
    for(int ti=0;ti<4;ti++){
      #pragma unroll
      for(int tj=0;tj<4;tj++){
        const int col = wc*64 + tj*16 + lrow;
        const float bi = bias ? bias[m0+col] : 0.f;
        #pragma unroll
        for(int r=0;r<4;r++){
          const int row = wr*64 + ti*16 + quad*4 + r;
          float val = acc[ti][tj][r] + bi;
          if(RELU) val = fmaxf(val, 0.f);
          Cs[row*128 + col] = f2fp8(val);
        }
      }
    }
    __syncthreads();
    #pragma unroll
    for(int p=0;p<4;p++){
      const int q = tid + p*256;
      const int row = q >> 3, c16 = (q & 7)*16;
      *(uintx4*)(&outb[(size_t)(n0+row)*M + m0 + c16]) =
          *(const uintx4*)(&Cs[row*128 + c16]);
    }
  } else {
    const int stn = (MODE==2) ? stn_p[0] : 0;
    #pragma unroll
    for(int ti=0;ti<4;ti++){
      #pragma unroll
      for(int r=0;r<4;r++){
        int row = n0 + wr*64 + ti*16 + quad*4 + r;
        int fidx = 0, trow = 0;
        if(MODE==2){ fidx = fire[row]; trow = row % TBLK; }
        #pragma unroll
        for(int tj=0;tj<4;tj++){
          int col = m0 + wc*64 + tj*16 + lrow;
          float val = acc[ti][tj][r];
          if(MODE==1){
            xout[(size_t)row*EDIM + col] += val + bias[col];
          } else {
            val = val*(1.f/256.f) + bias[col] + stat_emb[(size_t)stn*EDIM + col]
                + pe[trow*EDIM + col] + fire_emb[(size_t)fidx*EDIM + col];
            xout[(size_t)row*EDIM + col] = val;
          }
        }
      }
    }
  }
}

// ------- full-row GEMM + residual + LayerNorm epilogue (Wo only, K=384) -------
__global__ __launch_bounds__(512, 4) void gemm_row_ln(
    const unsigned char* __restrict__ A, const unsigned char* __restrict__ Wt,
    const float* __restrict__ bias, float* __restrict__ x,
    const float* __restrict__ g, const float* __restrict__ b,
    unsigned char* __restrict__ h, int K, int writeH){
  __shared__ __align__(16) unsigned char As[2][64*32];     // 2x2 KB
  __shared__ __align__(16) unsigned char Bs[2][384*32];    // 2x12 KB
  const int tid = threadIdx.x;
  const int n0 = blockIdx.x * 64;
  const int wave = tid >> 6, lane = tid & 63;
  const int rw = wave >> 1, cw = wave & 1;
  const int lrow = lane & 15, quad = lane >> 4;
  const int xsw = ((lane >> 2) & 1) << 4;
  floatx4 acc[12];
  #pragma unroll
  for(int j=0;j<12;j++) acc[j] = (floatx4){0.f,0.f,0.f,0.f};

  const int S = K >> 5;
  auto stage = [&](int s, int bi){
    const int kk = s*32;
    if(tid < 128){
      int r = tid >> 1, c = (((tid&1) ^ ((tid>>3)&1))) * 16;
      gld_lds16(&A[(size_t)(n0+r)*K + kk + c], &As[bi][tid*16]);
    }
    {
      int i = tid;
      int r = i >> 1, c = (((i&1) ^ ((i>>3)&1))) * 16;
      gld_lds16(&Wt[(size_t)r*K + kk + c], &Bs[bi][i*16]);
    }
    if(tid < 256){
      int i = tid + 512;
      int r = i >> 1, c = (((i&1) ^ ((i>>3)&1))) * 16;
      gld_lds16(&Wt[(size_t)r*K + kk + c], &Bs[bi][i*16]);
    }
  };
  stage(0, 0);
  for(int s=0; s<S; s++){
    const int bi = s & 1;
    __syncthreads();
    if(s+1 < S) stage(s+1, bi^1);
    long af = *(const long*)(&As[bi][(rw*16+lrow)*32 + ((quad*8) ^ xsw)]);
    long bfv[12];
    #pragma unroll
    for(int tj=0;tj<12;tj++)
      bfv[tj] = *(const long*)(&Bs[bi][(cw*192+tj*16+lrow)*32 + ((quad*8) ^ xsw)]);
    #pragma unroll
    for(int tj=0;tj<12;tj++)
      acc[tj] = __builtin_amdgcn_mfma_f32_16x16x32_fp8_fp8(af, bfv[tj], acc[tj], 0,0,0);
  }
  __syncthreads();
  float* part = (float*)&As[0][0];
  {
    float ps[4] = {0.f,0.f,0.f,0.f}, pq[4] = {0.f,0.f,0.f,0.f};
    #pragma unroll
    for(int tj=0;tj<12;tj++){
      const int col = cw*192 + tj*16 + lrow;
      const float bi = bias[col];
      #pragma unroll
      for(int r=0;r<4;r++){
        const int row = n0 + rw*16 + quad*4 + r;
        float v = acc[tj][r] + bi + x[(size_t)row*EDIM + col];
        acc[tj][r] = v;
        ps[r] += v; pq[r] += v*v;
      }
    }
    #pragma unroll
    for(int r=0;r<4;r++){
      #pragma unroll
      for(int m=1;m<16;m<<=1){ ps[r] += __shfl_xor(ps[r],m); pq[r] += __shfl_xor(pq[r],m); }
    }
    if(lrow == 0){
      #pragma unroll
      for(int r=0;r<4;r++){
        const int rl = rw*16 + quad*4 + r;
        part[rl*2 + cw]       = ps[r];
        part[128 + rl*2 + cw] = pq[r];
      }
    }
  }
  __syncthreads();
  #pragma unroll
  for(int r=0;r<4;r++){
    const int rl = rw*16 + quad*4 + r;
    const int row = n0 + rl;
    const float s = part[rl*2+0] + part[rl*2+1];
    const float q = part[128+rl*2+0] + part[128+rl*2+1];
    const float mean = s*(1.f/384.f);
    const float var  = q*(1.f/384.f) - mean*mean;
    const float rstd = rsqrtf(var + 1e-5f);
    #pragma unroll
    for(int tj=0;tj<12;tj++){
      const int col = cw*192 + tj*16 + lrow;
      const float v = acc[tj][r];
      x[(size_t)row*EDIM + col] = v;
      if(writeH)
        h[(size_t)row*EDIM + col] = f2fp8((v-mean)*rstd*g[col] + b[col]);
    }
  }
}

// ---------------- MFMA attention: one wave per (b,h), no cross-wave sync ------
__global__ __launch_bounds__(256) void attn_kernel(const unsigned char* __restrict__ qkv,
    unsigned char* __restrict__ o){
  __shared__ __align__(16) unsigned short lds[4*8064];   // 63 KB
  const int wave = threadIdx.x >> 6, lane = threadIdx.x & 63;
  const int bh = blockIdx.x*4 + wave;
  const int b = bh / NHEAD, h = bh % NHEAD;
  const int lrow = lane & 15, quad = lane >> 4;
  unsigned short* PT = lds + wave*8064;    // [48][72]
  unsigned short* VT = PT + 48*72;         // [64][72]
  const size_t base = (size_t)b*TBLK*QKVSTR + h*DHEAD;
  const unsigned char* qp = qkv + base;
  const unsigned char* kp = qkv + base + 384;
  const unsigned char* vp = qkv + base + 768;

  for(int s=0;s<64;s++){
    float v = (s < TBLK) ? fp82f(vp[(size_t)s*QKVSTR + lane]) : 0.f;
    VT[lane*72 + s] = f2bf(v);
  }
  #pragma unroll
  for(int i=lane;i<96;i+=64){
    int row = i >> 1, c = (i & 1)*8;
    *(short8*)(&PT[row*72 + 48 + c]) = (short8){0,0,0,0,0,0,0,0};
  }

  floatx4 accs[3][3];
  #pragma unroll
  for(int i=0;i<3;i++)
    #pragma unroll
    for(int j=0;j<3;j++) accs[i][j] = (floatx4){0.f,0.f,0.f,0.f};
  #pragma unroll
  for(int ks=0;ks<2;ks++){
    long aq[3], bk[3];
    #pragma unroll
    for(int ti=0;ti<3;ti++)
      aq[ti] = *(const long*)(qp + (size_t)(ti*16+lrow)*QKVSTR + ks*32 + quad*8);
    #pragma unroll
    for(int tj=0;tj<3;tj++)
      bk[tj] = *(const long*)(kp + (size_t)(tj*16+lrow)*QKVSTR + ks*32 + quad*8);
    #pragma unroll
    for(int ti=0;ti<3;ti++)
      #pragma unroll
      for(int tj=0;tj<3;tj++)
        accs[ti][tj] = __builtin_amdgcn_mfma_f32_16x16x32_fp8_fp8(aq[ti], bk[tj], accs[ti][tj], 0,0,0);
  }

  const float scale = 0.125f;
  #pragma unroll
  for(int ti=0;ti<3;ti++){
    #pragma unroll
    for(int r=0;r<4;r++){
      const int t = ti*16 + quad*4 + r;
      float pv[3]; float mx = -INFINITY;
      #pragma unroll
      for(int tj=0;tj<3;tj++){
        const int s = tj*16 + lrow;
        pv[tj] = (s <= t) ? accs[ti][tj][r]*scale : -INFINITY;
        mx = fmaxf(mx, pv[tj]);
      }
      #pragma unroll
      for(int m=1;m<16;m<<=1) mx = fmaxf(mx, __shfl_xor(mx, m));
      float sum = 0.f;
      #pragma unroll
      for(int tj=0;tj<3;tj++){ pv[tj] = __expf(pv[tj]-mx); sum += pv[tj]; }
      #pragma unroll
      for(int m=1;m<16;m<<=1) sum += __shfl_xor(sum, m);
      const float rs = 1.f/sum;
      #pragma unroll
      for(int tj=0;tj<3;tj++)
        PT[t*72 + tj*16 + lrow] = f2bf(pv[tj]*rs);
    }
  }

  floatx4 acco[3][4];
  #pragma unroll
  for(int i=0;i<3;i++)
    #pragma unroll
    for(int j=0;j<4;j++) acco[i][j] = (floatx4){0.f,0.f,0.f,0.f};
  #pragma unroll
  for(int ks=0;ks<2;ks++){
    short8 ap[3], bv[4];
    #pragma unroll
    for(int ti=0;ti<3;ti++)
      ap[ti] = *(const short8*)(&PT[(ti*16+lrow)*72 + ks*32 + quad*8]);
    #pragma unroll
    for(int td=0;td<4;td++)
      bv[td] = *(const short8*)(&VT[(td*16+lrow)*72 + ks*32 + quad*8]);
    #pragma unroll
    for(int ti=0;ti<3;ti++)
      #pragma unroll
      for(int td=0;td<4;td++)
        acco[ti][td] = __builtin_amdgcn_mfma_f32_16x16x32_bf16(ap[ti], bv[td], acco[ti][td], 0,0,0);
  }

  unsigned char* OB = (unsigned char*)VT;    // [48][80]
  #pragma unroll
  for(int ti=0;ti<3;ti++)
    #pragma unroll
    for(int td=0;td<4;td++)
      #pragma unroll
      for(int r=0;r<4;r++)
        OB[(ti*16+quad*4+r)*80 + td*16 + lrow] = f2fp8(acco[ti][td][r]);
  for(int i=lane;i<TBLK*4;i+=64){
    const int row = i >> 2, c16 = (i & 3)*16;
    *(uintx4*)(&o[((size_t)b*TBLK+row)*EDIM + h*DHEAD + c16]) =
        *(const uintx4*)(&OB[row*80 + c16]);
  }
}

// ---------------- head: LNf + sigmoid(x@Wh+bh)*500 + per-block partials -------
__global__ __launch_bounds__(256) void head_kernel(const float* __restrict__ x,
    const float* __restrict__ g, const float* __restrict__ b,
    const float* __restrict__ Wh, const float* __restrict__ bh,
    const int* __restrict__ targets, float* __restrict__ out,
    float* __restrict__ partials){
  const int wave = threadIdx.x >> 6, lane = threadIdx.x & 63;
  const int row = blockIdx.x*4 + wave;
  const float* xr = x + (size_t)row*EDIM;
  float v[6]; float s=0.f, sq=0.f;
  #pragma unroll
  for(int j=0;j<6;j++){ v[j]=xr[j*64+lane]; s+=v[j]; sq+=v[j]*v[j]; }
  #pragma unroll
  for(int m=1;m<64;m<<=1){ s += __shfl_xor(s,m); sq += __shfl_xor(sq,m); }
  const float mean = s*(1.f/384.f);
  const float var  = sq*(1.f/384.f) - mean*mean;
  const float rstd = rsqrtf(var + 1e-5f);
  float dot = 0.f;
  #pragma unroll
  for(int j=0;j<6;j++){
    int e = j*64+lane;
    float hh = (v[j]-mean)*rstd*g[e] + b[e];
    dot = fmaf(hh, Wh[e], dot);
  }
  #pragma unroll
  for(int m=1;m<64;m<<=1) dot += __shfl_xor(dot,m);
  __shared__ float part[4][4];
  if(lane == 0){
    float logit = 1.f/(1.f + __expf(-(dot + bh[0])));
    float den = logit * 500.f;
    out[row] = den;
    float tgt = (float)targets[(size_t)row*2];
    float nt  = tgt * (1.f/500.f);
    part[wave][0] = (logit-nt)*(logit-nt);
    part[wave][1] = (tgt-den)*(tgt-den);
    part[wave][2] = tgt;
    part[wave][3] = tgt*tgt;
  }
  __syncthreads();
  if(threadIdx.x < 4){
    float t0 = part[0][threadIdx.x] + part[1][threadIdx.x]
             + part[2][threadIdx.x] + part[3][threadIdx.x];
    partials[(size_t)threadIdx.x*NHBLK + blockIdx.x] = t0;
  }
}

// ---------------- final reduction: partials[4][NHBLK] -> mse, r2 --------------
__global__ __launch_bounds__(1024) void finalize_reduce(
    const float* __restrict__ partials, float* __restrict__ out){
  __shared__ float red[16];
  const int tid = threadIdx.x;
  const int c = tid >> 8, j = tid & 255;
  float s = 0.f;
  for(int i = j; i < NHBLK; i += 256) s += partials[(size_t)c*NHBLK + i];
  #pragma unroll
  for(int m=1;m<64;m<<=1) s += __shfl_xor(s,m);
  if((tid & 63) == 0) red[tid >> 6] = s;
  __syncthreads();
  if(tid == 0){
    float a0 = red[0]+red[1]+red[2]+red[3];
    float a1 = red[4]+red[5]+red[6]+red[7];
    float a2 = red[8]+red[9]+red[10]+red[11];
    float a3 = red[12]+red[13]+red[14]+red[15];
    const float n = (float)NTOK;
    out[NTOK]   = a0 / n;
    float denom = a3 - a2*a2/n;
    out[NTOK+1] = 1.f - a1/denom;
  }
}

// =============================================================================
extern "C" void kernel_launch(void* const* d_in, const int* in_sizes, int n_in,
                              void* d_out, int out_size, void* d_ws, size_t ws_size,
                              hipStream_t stream){
  (void)in_sizes; (void)n_in; (void)out_size; (void)ws_size;
  const int*   idx      = (const int*)  d_in[0];
  const int*   targets  = (const int*)  d_in[1];
  const int*   stn_ix   = (const int*)  d_in[3];
  const float* Wp       = (const float*)d_in[4];
  const float* bp       = (const float*)d_in[5];
  const float* stat_emb = (const float*)d_in[6];
  const float* fire_emb = (const float*)d_in[7];
  const float* ln1_g    = (const float*)d_in[8];
  const float* ln1_b    = (const float*)d_in[9];
  const float* Wq       = (const float*)d_in[10];
  const float* Wk       = (const float*)d_in[11];
  const float* Wv       = (const float*)d_in[12];
  const float* Wo       = (const float*)d_in[13];
  const float* bo       = (const float*)d_in[14];
  const float* ln2_g    = (const float*)d_in[15];
  const float* ln2_b    = (const float*)d_in[16];
  const float* W1       = (const float*)d_in[17];
  const float* b1       = (const float*)d_in[18];
  const float* W2       = (const float*)d_in[19];
  const float* b2       = (const float*)d_in[20];
  const float* lnf_g    = (const float*)d_in[21];
  const float* lnf_b    = (const float*)d_in[22];
  const float* Wh       = (const float*)d_in[23];
  const float* bh       = (const float*)d_in[24];
  float* out = (float*)d_out;

  char* ws = (char*)d_ws;
  float*         x      = (float*)        (ws + 0);
  unsigned char* h      = (unsigned char*)(ws + 56623104);
  unsigned char* qkv    = (unsigned char*)(ws + 84934656);
  unsigned char* obuf   = (unsigned char*)(ws + 169869312);
  unsigned char* ffn    = qkv;
  unsigned char* pm     = (unsigned char*)(ws + 169869312);  // aliases obuf
  int*           fire   = (int*)          (ws + 186384384);
  unsigned char* wp_t   = (unsigned char*)(ws + 186531840);
  float*         pe     = (float*)        (ws + 186703872);
  float*         partials = (float*)      (ws + 169869312);  // aliases obuf
  unsigned char* wqkv_t = (unsigned char*)(ws + 198180864);
  unsigned char* wo_t   = (unsigned char*)(ws + 203489280);
  unsigned char* w1_t   = (unsigned char*)(ws + 205258752);
  unsigned char* w2_t   = (unsigned char*)(ws + 212336640);

  const dim3 tb(32,8);
  wt_transpose<<<dim3(12,12,6), tb, 0, stream>>>(Wq, wqkv_t,          384,  384, 442368);
  wt_transpose<<<dim3(12,12,6), tb, 0, stream>>>(Wk, wqkv_t + 147456, 384,  384, 442368);
  wt_transpose<<<dim3(12,12,6), tb, 0, stream>>>(Wv, wqkv_t + 294912, 384,  384, 442368);
  wt_transpose<<<dim3(12,12,6), tb, 0, stream>>>(Wo, wo_t,            384,  384, 147456);
  wt_transpose<<<dim3(48,12,6), tb, 0, stream>>>(W1, w1_t,            384, 1536, 589824);
  wt_transpose<<<dim3(12,48,6), tb, 0, stream>>>(W2, w2_t,           1536,  384, 589824);
  wp_transpose<<<384, 256, 0, stream>>>(Wp, wp_t);
  pe_kernel<<<TBLK, 384, 0, stream>>>(pe);
  prep_pm<<<(NTOK*KPM + 255)/256, 256, 0, stream>>>(idx, pm);
  prep_fire<<<(NTOK + 255)/256, 256, 0, stream>>>(idx, stn_ix, fire);

  // embed GEMM: x = (pm*256) @ wp_t^T / 256 + (bp + stat + pe + fire_emb)
  gemm_k<2,false><<<dim3(3,288), 256, 0, stream>>>(pm, wp_t, bp, nullptr, x,
      fire, pe, stat_emb, stn_ix, fire_emb, 384, KPM);

  // layer-0 ln1
  ln_act<<<NTOK/4, 256, 0, stream>>>(x, ln1_g, ln1_b, h);

  const dim3 gQKV(9, 288);
  const dim3 gE(3, 288);
  const dim3 gF(12, 288);
  for(int l=0; l<NLAYER; l++){
    gemm_k<0,false><<<gQKV, 256, 0, stream>>>(h, wqkv_t + (size_t)l*442368,
        nullptr, qkv, nullptr, nullptr, nullptr, nullptr, nullptr, nullptr, 1152, 384);
    attn_kernel<<<BSZ*NHEAD/4, 256, 0, stream>>>(qkv, obuf);
    // x += obuf@Wo + bo;  h = LN2(x)   (fused; K=384)
    gemm_row_ln<<<NTOK/64, 512, 0, stream>>>(obuf, wo_t + (size_t)l*147456,
        bo + l*EDIM, x, ln2_g + l*EDIM, ln2_b + l*EDIM, h, 384, 1);
    gemm_k<0,true><<<gF, 256, 0, stream>>>(h, w1_t + (size_t)l*589824,
        b1 + l*1536, ffn, nullptr, nullptr, nullptr, nullptr, nullptr, nullptr, 1536, 384);
    // x += ffn@W2 + b2   (fp8, fp32 residual epilogue)
    gemm_k<1,false><<<gE, 256, 0, stream>>>(ffn, w2_t + (size_t)l*589824,
        b2 + l*EDIM, nullptr, x, nullptr, nullptr, nullptr, nullptr, nullptr, 384, 1536);
    // h = LN1[l+1](x)  (skip on last layer; head does LNf itself)
    if(l < NLAYER-1)
      ln_act<<<NTOK/4, 256, 0, stream>>>(x, ln1_g + (l+1)*EDIM, ln1_b + (l+1)*EDIM, h);
  }

  head_kernel<<<NHBLK, 256, 0, stream>>>(x, lnf_g, lnf_b, Wh, bh, targets, out, partials);
  finalize_reduce<<<1, 1024, 0, stream>>>(partials, out);
}